// Round 17
// baseline (59.396 us; speedup 1.0000x reference)
//
#include <hip/hip_runtime.h>
#include <math.h>

constexpr int M_TOK = 8;
constexpr int N_OUT = 8192;
constexpr int K_IN  = 8192;
constexpr int KG    = 64;   // K / G, G = 128
constexpr int R_N   = 4;    // output rows per wave

typedef int   i32x4 __attribute__((ext_vector_type(4)));
typedef float f32x4 __attribute__((ext_vector_type(4)));

// ---------------- Kernel 1: per-token int8 quant -> int8 CODES + per-row scale ----------------
__global__ __launch_bounds__(1024) void act_quant_kernel(const float* __restrict__ x,
                                                         signed char* __restrict__ xq8,
                                                         float* __restrict__ srow) {
    const int row = blockIdx.x;
    const f32x4* xr = reinterpret_cast<const f32x4*>(x + (size_t)row * K_IN);
    const int tid = threadIdx.x;

    f32x4 v0 = xr[tid * 2];
    f32x4 v1 = xr[tid * 2 + 1];

    float m = fmaxf(
        fmaxf(fmaxf(fabsf(v0.x), fabsf(v0.y)), fmaxf(fabsf(v0.z), fabsf(v0.w))),
        fmaxf(fmaxf(fabsf(v1.x), fabsf(v1.y)), fmaxf(fabsf(v1.z), fabsf(v1.w))));

    #pragma unroll
    for (int off = 32; off; off >>= 1) m = fmaxf(m, __shfl_xor(m, off));

    __shared__ float smax[16];
    if ((tid & 63) == 0) smax[tid >> 6] = m;
    __syncthreads();
    float mm = smax[0];
    #pragma unroll
    for (int i = 1; i < 16; ++i) mm = fmaxf(mm, smax[i]);

    const float s = fmaxf(mm / 127.0f, 1e-8f);   // numpy: true div, clamp
    if (tid == 0) srow[row] = s;

    auto qcode = [&](float v) -> int {
        float q = rintf(v / s);              // numpy round = half-to-even
        q = fminf(fmaxf(q, -127.0f), 127.0f);
        return (int)q;
    };

    const int q0 = qcode(v0.x) & 255, q1 = qcode(v0.y) & 255,
              q2 = qcode(v0.z) & 255, q3 = qcode(v0.w) & 255;
    const int q4 = qcode(v1.x) & 255, q5 = qcode(v1.y) & 255,
              q6 = qcode(v1.z) & 255, q7 = qcode(v1.w) & 255;
    int2 p;
    p.x = q0 | (q1 << 8) | (q2 << 16) | (q3 << 24);
    p.y = q4 | (q5 << 8) | (q6 << 16) | (q7 << 24);
    reinterpret_cast<int2*>(xq8 + (size_t)row * K_IN)[tid] = p;
}

// ---------------- Kernel 2: staggered dequant-GEMM, LDS codes + intra-wave row stagger ----------------
// r16 skeleton (LDS-resident codes, unique per-wave phase @16 B: 54.4 us).
// Single change: the wave's 4 weight-row streams get per-row phase offsets
// r*8 KiB. Rows all start at multiples of 32 KiB (congruent mod channel
// interleave), so same-k loads put 4 simultaneous requests on the same
// channel subset; the offsets spread them to 4 distinct channel phases.
// Each row still covers every 256-chunk exactly once; per-(r,m) sums
// unchanged, fixed order -> deterministic. Cost: xv unpack per row (x4 VALU).
// Win ledger: stagger r9(-9) r12(-2.8) r16(-0.8), LDS codes r15(-1.6).
// REGRESSED: r3 rotate, r8 nt, r10 barrier dbuf, r11 burst, r13 splitK, r14 vmcnt pf.
__global__ __launch_bounds__(256) void qlin_kernel(const signed char* __restrict__ xq8,
                                                   const float* __restrict__ srow,
                                                   const int* __restrict__ qw,
                                                   const float* __restrict__ scales,
                                                   const float* __restrict__ bias,
                                                   float* __restrict__ out) {
    __shared__ int xsm[M_TOK * K_IN / 4];   // 64 KiB of int8 codes

    const int widx = threadIdx.x >> 6;
    const int lane = threadIdx.x & 63;
    const int wave = blockIdx.x * 4 + widx;
    const int n0 = wave * R_N;
    const int lk = lane * 4;
    const int phase = (wave * 4) & (K_IN - 1);   // unique per-wave, 16 B granularity

    // one-time cooperative LDS fill: 4096 i32x4 chunks / 256 threads = 16 each
    {
        const i32x4* src = reinterpret_cast<const i32x4*>(xq8);
        i32x4* dst = reinterpret_cast<i32x4*>(xsm);
        #pragma unroll
        for (int j = 0; j < 16; ++j)
            dst[j * 256 + threadIdx.x] = src[j * 256 + threadIdx.x];
    }
    __syncthreads();   // only barrier; loop below is free-running

    float acc[R_N][M_TOK];
    #pragma unroll
    for (int r = 0; r < R_N; ++r)
        #pragma unroll
        for (int m = 0; m < M_TOK; ++m) acc[r][m] = 0.0f;

    for (int t = 0; t < 32; ++t) {
        // issue all 4 weight loads first (4 distinct channel phases), then compute
        int   kk[R_N];
        i32x4 cw[R_N];
        #pragma unroll
        for (int r = 0; r < R_N; ++r) {       // unroll-constant indexing only
            kk[r] = (phase + t * 256 + r * 2048 + lk) & (K_IN - 1);
            cw[r] = *reinterpret_cast<const i32x4*>(qw + (size_t)(n0 + r) * K_IN + kk[r]);
        }

        #pragma unroll
        for (int r = 0; r < R_N; ++r) {
            const int k  = kk[r];
            const int g  = k >> 7;    // per-lane scale-group index
            const int kd = k >> 2;    // dword index within a row

            const float sc = scales[(size_t)(n0 + r) * KG + g];
            const float w0 = (float)cw[r].x * sc;
            const float w1 = (float)cw[r].y * sc;
            const float w2 = (float)cw[r].z * sc;
            const float w3 = (float)cw[r].w * sc;

            #pragma unroll
            for (int m = 0; m < M_TOK; ++m) {
                const int d = xsm[m * 2048 + kd];
                float a = acc[r][m];
                a = fmaf(w0, (float)((d << 24) >> 24), a);
                a = fmaf(w1, (float)((d << 16) >> 24), a);
                a = fmaf(w2, (float)((d << 8) >> 24), a);
                a = fmaf(w3, (float)(d >> 24), a);
                acc[r][m] = a;
            }
        }
    }

    // full butterfly reduce -> every lane holds each (r,m) total
    #pragma unroll
    for (int r = 0; r < R_N; ++r)
        #pragma unroll
        for (int m = 0; m < M_TOK; ++m) {
            float v = acc[r][m];
            #pragma unroll
            for (int off = 32; off; off >>= 1) v += __shfl_xor(v, off);
            acc[r][m] = v;
        }

    // lane (r*8 + m) writes out[m][n0+r] = s_m * acc + bias  (static-index chain)
    if (lane < R_N * M_TOK) {
        const int rsel = lane >> 3;
        const int msel = lane & 7;
        float myv = 0.0f;
        #pragma unroll
        for (int r = 0; r < R_N; ++r)
            #pragma unroll
            for (int m = 0; m < M_TOK; ++m)
                if (r == rsel && m == msel) myv = acc[r][m] * srow[m];
        out[(size_t)msel * N_OUT + n0 + rsel] = myv + bias[n0 + rsel];
    }
}

extern "C" void kernel_launch(void* const* d_in, const int* in_sizes, int n_in,
                              void* d_out, int out_size, void* d_ws, size_t ws_size,
                              hipStream_t stream) {
    const float* x      = (const float*)d_in[0];
    const int*   qw     = (const int*)d_in[1];
    const float* scales = (const float*)d_in[2];
    const float* bias   = (const float*)d_in[3];
    float* out = (float*)d_out;

    float*       srow = (float*)d_ws;                       // 8 floats (pad to 256 B)
    signed char* xq8  = (signed char*)d_ws + 256;           // M*K int8 = 64 KiB

    act_quant_kernel<<<M_TOK, 1024, 0, stream>>>(x, xq8, srow);

    const int waves  = N_OUT / R_N;        // 2048
    const int blocks = waves / 4;          // 512 blocks x 256 threads
    qlin_kernel<<<blocks, 256, 0, stream>>>(xq8, srow, qw, scales, bias, out);
}

// Round 18
// 53.901 us; speedup vs baseline: 1.1019x; 1.1019x over previous
//
#include <hip/hip_runtime.h>
#include <math.h>

constexpr int M_TOK = 8;
constexpr int N_OUT = 8192;
constexpr int K_IN  = 8192;
constexpr int KG    = 64;   // K / G, G = 128
constexpr int R_N   = 4;    // output rows per wave

typedef int   i32x4 __attribute__((ext_vector_type(4)));
typedef float f32x4 __attribute__((ext_vector_type(4)));

// ---------------- Kernel 1: per-token int8 quant -> int8 CODES + per-row scale ----------------
__global__ __launch_bounds__(1024) void act_quant_kernel(const float* __restrict__ x,
                                                         signed char* __restrict__ xq8,
                                                         float* __restrict__ srow) {
    const int row = blockIdx.x;
    const f32x4* xr = reinterpret_cast<const f32x4*>(x + (size_t)row * K_IN);
    const int tid = threadIdx.x;

    f32x4 v0 = xr[tid * 2];
    f32x4 v1 = xr[tid * 2 + 1];

    float m = fmaxf(
        fmaxf(fmaxf(fabsf(v0.x), fabsf(v0.y)), fmaxf(fabsf(v0.z), fabsf(v0.w))),
        fmaxf(fmaxf(fabsf(v1.x), fabsf(v1.y)), fmaxf(fabsf(v1.z), fabsf(v1.w))));

    #pragma unroll
    for (int off = 32; off; off >>= 1) m = fmaxf(m, __shfl_xor(m, off));

    __shared__ float smax[16];
    if ((tid & 63) == 0) smax[tid >> 6] = m;
    __syncthreads();
    float mm = smax[0];
    #pragma unroll
    for (int i = 1; i < 16; ++i) mm = fmaxf(mm, smax[i]);

    const float s = fmaxf(mm / 127.0f, 1e-8f);   // numpy: true div, clamp
    if (tid == 0) srow[row] = s;

    auto qcode = [&](float v) -> int {
        float q = rintf(v / s);              // numpy round = half-to-even
        q = fminf(fmaxf(q, -127.0f), 127.0f);
        return (int)q;
    };

    const int q0 = qcode(v0.x) & 255, q1 = qcode(v0.y) & 255,
              q2 = qcode(v0.z) & 255, q3 = qcode(v0.w) & 255;
    const int q4 = qcode(v1.x) & 255, q5 = qcode(v1.y) & 255,
              q6 = qcode(v1.z) & 255, q7 = qcode(v1.w) & 255;
    int2 p;
    p.x = q0 | (q1 << 8) | (q2 << 16) | (q3 << 24);
    p.y = q4 | (q5 << 8) | (q6 << 16) | (q7 << 24);
    reinterpret_cast<int2*>(xq8 + (size_t)row * K_IN)[tid] = p;
}

// ---------------- Kernel 2: staggered dequant-GEMM, LDS codes, alternating sweep ----------------
// r16 skeleton EXACTLY (LDS-resident codes, unique per-wave phase @16 B,
// shared xv unpack: 54.4 us) + ONE zero-cost change: odd waves sweep k
// DOWNWARD. All streams advancing in one direction present a coherent
// address front to each channel; alternating direction interleaves
// ascending/descending fronts. Byte-identical traffic, no extra VALU,
// fixed per-wave accumulation order -> deterministic.
// Win ledger: stagger r9(-9) r12(-2.8) r16(-0.8), LDS codes r15(-1.6).
// REGRESSED: r3 rotate, r8 nt, r10 barrier dbuf, r11 burst, r13 splitK,
// r14 vmcnt pf, r17 per-row-k stagger (4x unpack cost swamped the gain).
__global__ __launch_bounds__(256) void qlin_kernel(const signed char* __restrict__ xq8,
                                                   const float* __restrict__ srow,
                                                   const int* __restrict__ qw,
                                                   const float* __restrict__ scales,
                                                   const float* __restrict__ bias,
                                                   float* __restrict__ out) {
    __shared__ int xsm[M_TOK * K_IN / 4];   // 64 KiB of int8 codes

    const int widx = threadIdx.x >> 6;
    const int lane = threadIdx.x & 63;
    const int wave = blockIdx.x * 4 + widx;
    const int n0 = wave * R_N;
    const int lk = lane * 4;
    const int phase = (wave * 4) & (K_IN - 1);        // unique per-wave, 16 B gran
    const int step  = (wave & 1) ? -256 : 256;        // alternating sweep direction

    // one-time cooperative LDS fill: 4096 i32x4 chunks / 256 threads = 16 each
    {
        const i32x4* src = reinterpret_cast<const i32x4*>(xq8);
        i32x4* dst = reinterpret_cast<i32x4*>(xsm);
        #pragma unroll
        for (int j = 0; j < 16; ++j)
            dst[j * 256 + threadIdx.x] = src[j * 256 + threadIdx.x];
    }
    __syncthreads();   // only barrier; loop below is free-running

    float acc[R_N][M_TOK];
    #pragma unroll
    for (int r = 0; r < R_N; ++r)
        #pragma unroll
        for (int m = 0; m < M_TOK; ++m) acc[r][m] = 0.0f;

    for (int t = 0; t < 32; ++t) {
        const int k = (int)(((unsigned)(phase + t * step + lk)) & (K_IN - 1));  // mult of 4
        const int g = k >> 7;   // per-lane scale-group index
        const int kd = k >> 2;  // dword index within a row

        // unpack activation codes from LDS: q exact, scale deferred to epilogue
        f32x4 xv[M_TOK];
        #pragma unroll
        for (int m = 0; m < M_TOK; ++m) {
            const int d = xsm[m * 2048 + kd];
            xv[m].x = (float)((d << 24) >> 24);
            xv[m].y = (float)((d << 16) >> 24);
            xv[m].z = (float)((d << 8) >> 24);
            xv[m].w = (float)(d >> 24);
        }

        #pragma unroll
        for (int r = 0; r < R_N; ++r) {
            const i32x4 c =
                *reinterpret_cast<const i32x4*>(qw + (size_t)(n0 + r) * K_IN + k);
            const float sc = scales[(size_t)(n0 + r) * KG + g];
            const float w0 = (float)c.x * sc;
            const float w1 = (float)c.y * sc;
            const float w2 = (float)c.z * sc;
            const float w3 = (float)c.w * sc;
            #pragma unroll
            for (int m = 0; m < M_TOK; ++m) {
                float a = acc[r][m];
                a = fmaf(w0, xv[m].x, a);
                a = fmaf(w1, xv[m].y, a);
                a = fmaf(w2, xv[m].z, a);
                a = fmaf(w3, xv[m].w, a);
                acc[r][m] = a;
            }
        }
    }

    // full butterfly reduce -> every lane holds each (r,m) total
    #pragma unroll
    for (int r = 0; r < R_N; ++r)
        #pragma unroll
        for (int m = 0; m < M_TOK; ++m) {
            float v = acc[r][m];
            #pragma unroll
            for (int off = 32; off; off >>= 1) v += __shfl_xor(v, off);
            acc[r][m] = v;
        }

    // lane (r*8 + m) writes out[m][n0+r] = s_m * acc + bias  (static-index chain)
    if (lane < R_N * M_TOK) {
        const int rsel = lane >> 3;
        const int msel = lane & 7;
        float myv = 0.0f;
        #pragma unroll
        for (int r = 0; r < R_N; ++r)
            #pragma unroll
            for (int m = 0; m < M_TOK; ++m)
                if (r == rsel && m == msel) myv = acc[r][m] * srow[m];
        out[(size_t)msel * N_OUT + n0 + rsel] = myv + bias[n0 + rsel];
    }
}

extern "C" void kernel_launch(void* const* d_in, const int* in_sizes, int n_in,
                              void* d_out, int out_size, void* d_ws, size_t ws_size,
                              hipStream_t stream) {
    const float* x      = (const float*)d_in[0];
    const int*   qw     = (const int*)d_in[1];
    const float* scales = (const float*)d_in[2];
    const float* bias   = (const float*)d_in[3];
    float* out = (float*)d_out;

    float*       srow = (float*)d_ws;                       // 8 floats (pad to 256 B)
    signed char* xq8  = (signed char*)d_ws + 256;           // M*K int8 = 64 KiB

    act_quant_kernel<<<M_TOK, 1024, 0, stream>>>(x, xq8, srow);

    const int waves  = N_OUT / R_N;        // 2048
    const int blocks = waves / 4;          // 512 blocks x 256 threads
    qlin_kernel<<<blocks, 256, 0, stream>>>(xq8, srow, qw, scales, bias, out);
}